// Round 14
// baseline (221.844 us; speedup 1.0000x reference)
//
#include <hip/hip_runtime.h>
#include <hip/hip_fp16.h>
#include <stdint.h>

#define FP8_MAX_V 448.0f
#define BM 256
#define BN 256
#define BKB 128  // K-bytes per tile step (fp8 => 128 elements); LDS row = 128 B

typedef float floatx4 __attribute__((ext_vector_type(4)));
typedef int intx4 __attribute__((ext_vector_type(4)));
typedef int intx8 __attribute__((ext_vector_type(8)));

// asm wait/barrier with full compiler fencing (rule #18).
#define WAITVM(n)                                              \
  do {                                                         \
    asm volatile("s_waitcnt vmcnt(" #n ")" ::: "memory");      \
    __builtin_amdgcn_sched_barrier(0);                         \
  } while (0)
#define BARRIER()                                              \
  do {                                                         \
    __builtin_amdgcn_sched_barrier(0);                         \
    __builtin_amdgcn_s_barrier();                              \
    __builtin_amdgcn_sched_barrier(0);                         \
  } while (0)

// Deterministic bf16 round-to-nearest-even of an fp32 value, returned widened to fp32.
__device__ __forceinline__ float bf16_rne(float v) {
  uint32_t u = __float_as_uint(v);
  u = (u + 0x7fffu + ((u >> 16) & 1u)) & 0xffff0000u;
  return __uint_as_float(u);
}

// Pack 4 fp32 (already clipped to +-448) into 4 OCP e4m3fn bytes via HW RNE cvt.
__device__ __forceinline__ uint32_t pack4_fp8(float a, float b, float c, float d) {
  int p = 0;
  p = __builtin_amdgcn_cvt_pk_fp8_f32(a, b, p, false);  // bytes 0..1
  p = __builtin_amdgcn_cvt_pk_fp8_f32(c, d, p, true);   // bytes 2..3
  return (uint32_t)p;
}

__device__ __forceinline__ void gload_lds16(const uint8_t* g, uint8_t* l) {
  __builtin_amdgcn_global_load_lds(
      (const __attribute__((address_space(1))) uint32_t*)g,
      (__attribute__((address_space(3))) uint32_t*)l,
      16, 0, 0);
}

// Fused per-row quantization for BOTH x (blocks 0..M-1) and w (blocks M..M+N-1):
// amax over K -> scale -> fp8. Weight path fp16-round-trips the scale (matches
// reference's scale.astype(fp16).astype(fp32)).
__global__ __launch_bounds__(256) void quant_all_kernel(
    const float* __restrict__ x, const float* __restrict__ w,
    uint8_t* __restrict__ x8, uint8_t* __restrict__ w8,
    float* __restrict__ asc, float* __restrict__ wsc, int M, int K) {
  const int blk = blockIdx.x;
  const bool isW = blk >= M;
  const int row = isW ? (blk - M) : blk;
  const float* rp = (isW ? w : x) + (size_t)row * K;
  uint8_t* out8 = (isW ? w8 : x8) + (size_t)row * K;
  float* scp = (isW ? wsc : asc) + row;
  const int tid = threadIdx.x;

  // K = 4096: 16 floats/thread as 4x float4, coalesced (stride-256 float4s).
  float4 v[4];
  float amax = 0.f;
#pragma unroll
  for (int i = 0; i < 4; ++i) {
    v[i] = ((const float4*)rp)[i * 256 + tid];
    amax = fmaxf(amax, fmaxf(fmaxf(fabsf(v[i].x), fabsf(v[i].y)),
                             fmaxf(fabsf(v[i].z), fabsf(v[i].w))));
  }
#pragma unroll
  for (int off = 32; off; off >>= 1) amax = fmaxf(amax, __shfl_xor(amax, off));
  __shared__ float red[4];
  if ((tid & 63) == 0) red[tid >> 6] = amax;
  __syncthreads();
  amax = fmaxf(fmaxf(red[0], red[1]), fmaxf(red[2], red[3]));

  float scale = fmaxf(amax / FP8_MAX_V, 1e-6f);
  if (isW) scale = __half2float(__float2half(scale));  // RNE fp16 round-trip
  if (tid == 0) *scp = scale;

  uint32_t* op = (uint32_t*)out8;
#pragma unroll
  for (int i = 0; i < 4; ++i) {
    // true fp32 division (correctly rounded) to match numpy's x / scale
    float qa = fminf(fmaxf(v[i].x / scale, -FP8_MAX_V), FP8_MAX_V);
    float qb = fminf(fmaxf(v[i].y / scale, -FP8_MAX_V), FP8_MAX_V);
    float qc = fminf(fmaxf(v[i].z / scale, -FP8_MAX_V), FP8_MAX_V);
    float qd = fminf(fmaxf(v[i].w / scale, -FP8_MAX_V), FP8_MAX_V);
    op[i * 256 + tid] = pack4_fp8(qa, qb, qc, qd);
  }
}

// C[t,o] = sum_k A8[t,k]*B8[o,k]  (both K-major), scaled + bias + bf16 round.
// r13 counted-vmcnt schedule + INTRA-TILE SOFTWARE PIPELINE: a-fragment
// ds_reads issue ONE PHASE AHEAD of their MFMA cluster, with no barrier or
// sched fence between read(p+1) and MFMA(p) -> compiler emits counted lgkm
// waits and the matrix pipe retires phase p while phase p+1's reads return.
//   256x256 tile, 512 thr = 8 waves (2M x 4N), wave-tile 128x64 = 8x4 frags
//   of mfma_scale_f32_16x16x128_f8f6f4, UNIT scales (e8m0 0x7F = 1.0).
//   A,B double-buffered (128 KB LDS, 1 block/CU).
// Per-tile schedule (2 barriers, waits counted, never 0 until tail):
//   stageB1(t+1); WAITVM(4); BARRIER;          // B(t),A1(t) drained+visible
//   read b[4] + a01;
//   stageB2(t+1); WAITVM(4); BARRIER;          // A2(t) drained+visible
//   read a23; MFMA8(0,a01);
//   stageA1(t+1); read a45; MFMA8(1,a23);
//   stageA2(t+1); read a67; MFMA8(2,a45);
//   MFMA8(3,a67);
// vmcnt ledger (steady, entry=8): +B1=10, WAITVM(4) drains B1,B2,A1(t);
// +B2=6, WAITVM(4) drains A2(t); +A1,+A2=8 at exit. Tail: WAITVM(2)/WAITVM(0).
// Race-audit: b-reads lie between barrier1(t) and barrier2(t), B-buffer
// rewrite issues after barrier2 one tile later; a67 tail-read precedes the
// wave's barrier1(t+1), A-rewrite issues after barrier2(t+1) -> safe.
// A1 unit = LDS row-gloads {0,2} (tile rows 0-63,128-191) covers a01,a23 for
// both wr; A2 = {1,3} covers a45,a67.
__global__ __launch_bounds__(512, 2) void gemm_fp8_kernel(
    const uint8_t* __restrict__ A8, const uint8_t* __restrict__ B8,
    const float* __restrict__ asc, const float* __restrict__ wsc,
    const float* __restrict__ bias, float* __restrict__ out,
    int M, int N, int K) {
  __shared__ __align__(16) uint8_t As[2][BM * BKB];  // 2 x 32 KB
  __shared__ __align__(16) uint8_t Bs[2][BN * BKB];  // 2 x 32 KB

  const int tid = threadIdx.x;
  const int lane = tid & 63;
  const int wid = tid >> 6;
  const int wr = wid >> 2;  // 0..1 (M dimension, 128 rows)
  const int wc = wid & 3;   // 0..3 (N dimension, 64 cols)

  const int ntn = N / BN;
  const int bm = blockIdx.x / ntn;
  const int bn = blockIdx.x % ntn;

  floatx4 acc[8][4] = {};

  // Staging: thread tid -> LDS linear offset tid*16 (row=tid>>3, c16=tid&7),
  // global source chunk = (tid&7) ^ (row&7). Row stride 64 between gloads
  // preserves (row&7), so one source offset serves all.
  const int srow = tid >> 3;                      // 0..63
  const int sc_log = (tid & 7) ^ (srow & 7);      // pre-swizzled source chunk
  const uint8_t* gA = A8 + (size_t)(bm * BM + srow) * K + sc_log * 16;
  const uint8_t* gB = B8 + (size_t)(bn * BN + srow) * K + sc_log * 16;
  const size_t rstep = (size_t)64 * K;

  const int fr = lane & 15;        // fragment row/col within 16
  const int hi = lane >> 4;        // 0..3: K-block of 32 elems within the 128-tile
  const int fsw = fr & 7;          // read-side swizzle key
  // Lane's 32B fragment = chunks {2*hi, 2*hi+1}, each XOR-swizzled.
  const int cls = ((2 * hi) ^ fsw) * 16;      // low 16B chunk byte offset
  const int chs = ((2 * hi + 1) ^ fsw) * 16;  // high 16B chunk byte offset

  // Stage units: 2 gload_lds each. A row-gload i covers tile rows [64i,64i+64).
  auto stageB1 = [&](int buf, int k0) {
    uint8_t* lB = Bs[buf] + tid * 16;
    gload_lds16(gB + 0 * rstep + k0, lB + 0 * 8192);
    gload_lds16(gB + 1 * rstep + k0, lB + 1 * 8192);
  };
  auto stageB2 = [&](int buf, int k0) {
    uint8_t* lB = Bs[buf] + tid * 16;
    gload_lds16(gB + 2 * rstep + k0, lB + 2 * 8192);
    gload_lds16(gB + 3 * rstep + k0, lB + 3 * 8192);
  };
  auto stageA1 = [&](int buf, int k0) {  // rows 0-63 & 128-191 (a01,a23 both wr)
    uint8_t* lA = As[buf] + tid * 16;
    gload_lds16(gA + 0 * rstep + k0, lA + 0 * 8192);
    gload_lds16(gA + 2 * rstep + k0, lA + 2 * 8192);
  };
  auto stageA2 = [&](int buf, int k0) {  // rows 64-127 & 192-255 (a45,a67)
    uint8_t* lA = As[buf] + tid * 16;
    gload_lds16(gA + 1 * rstep + k0, lA + 1 * 8192);
    gload_lds16(gA + 3 * rstep + k0, lA + 3 * 8192);
  };

  auto loadB = [&](intx8* b, int buf) {
#pragma unroll
    for (int n = 0; n < 4; ++n) {
      const uint8_t* p = Bs[buf] + (size_t)(wc * 64 + n * 16 + fr) * BKB;
      intx4 lo = *(const intx4*)(p + cls);
      intx4 hh = *(const intx4*)(p + chs);
      b[n] = (intx8){lo.x, lo.y, lo.z, lo.w, hh.x, hh.y, hh.z, hh.w};
    }
  };
  auto loadA2f = [&](intx8* a, int buf, int ph) {
#pragma unroll
    for (int j = 0; j < 2; ++j) {
      const uint8_t* p = As[buf] + (size_t)(wr * 128 + (2 * ph + j) * 16 + fr) * BKB;
      intx4 lo = *(const intx4*)(p + cls);
      intx4 hh = *(const intx4*)(p + chs);
      a[j] = (intx8){lo.x, lo.y, lo.z, lo.w, hh.x, hh.y, hh.z, hh.w};
    }
  };

#define MFMA8(ph, a, b)                                                       \
  do {                                                                        \
    __builtin_amdgcn_s_setprio(1);                                            \
    _Pragma("unroll") for (int j = 0; j < 2; ++j)                             \
        _Pragma("unroll") for (int n = 0; n < 4; ++n)                         \
        acc[2 * (ph) + j][n] = __builtin_amdgcn_mfma_scale_f32_16x16x128_f8f6f4( \
            (a)[j], (b)[n], acc[2 * (ph) + j][n], 0, 0, 0,                    \
            0x7F7F7F7F, 0, 0x7F7F7F7F);                                       \
    __builtin_amdgcn_s_setprio(0);                                            \
  } while (0)

  const int NT = K / BKB;  // 32
  // Prologue (issue order defines the vmcnt ledger): B1,B2,A1,A2 of tile 0.
  stageB1(0, 0); stageB2(0, 0); stageA1(0, 0); stageA2(0, 0);  // 8 in flight

  for (int t = 0; t < NT; ++t) {
    const int cur = t & 1, nxt = cur ^ 1;
    const int k1 = (t + 1) * BKB;
    intx8 b[4], a01[2], a23[2], a45[2], a67[2];

    // ---- barrier 1: B(t) + A1(t) resident
    if (t + 1 < NT) { stageB1(nxt, k1); WAITVM(4); } else { WAITVM(2); }
    BARRIER();
    loadB(b, cur);
    loadA2f(a01, cur, 0);

    // ---- barrier 2: A2(t) resident (a01/b reads above are pre-barrier safe:
    //      they only touch B(t)+A1(t))
    if (t + 1 < NT) { stageB2(nxt, k1); WAITVM(4); } else { WAITVM(0); }
    BARRIER();

    // ---- pipelined phases: read(p+1) issues before MFMA(p), no fences between
    loadA2f(a23, cur, 1);
    MFMA8(0, a01, b);
    if (t + 1 < NT) stageA1(nxt, k1);
    loadA2f(a45, cur, 2);
    MFMA8(1, a23, b);
    if (t + 1 < NT) stageA2(nxt, k1);
    loadA2f(a67, cur, 3);
    MFMA8(2, a45, b);
    MFMA8(3, a67, b);
  }
#undef MFMA8

  // Epilogue: C/D 16x16 layout col=lane&15, row=(lane>>4)*4+r (dtype-independent;
  // f8f6f4-scaled C/D layout is shape-determined per m121-m128).
  const int rbase = bm * BM + wr * 128;
  const int cbase = bn * BN + wc * 64;
#pragma unroll
  for (int n = 0; n < 4; ++n) {
    const int col = cbase + n * 16 + fr;
    const float wv = wsc[col];
    const float bb = bf16_rne(bias[col]);  // bias.astype(bf16).astype(f32)
#pragma unroll
    for (int m = 0; m < 8; ++m) {
      const int r0 = rbase + m * 16 + hi * 4;
#pragma unroll
      for (int r = 0; r < 4; ++r) {
        const int row = r0 + r;
        // reference order: (acc * act_scale) * w_scale + bias_bf16, then bf16 RNE
        float v = (acc[m][n][r] * asc[row]) * wv + bb;
        out[(size_t)row * N + col] = bf16_rne(v);
      }
    }
  }
}

extern "C" void kernel_launch(void* const* d_in, const int* in_sizes, int n_in,
                              void* d_out, int out_size, void* d_ws, size_t ws_size,
                              hipStream_t stream) {
  const float* x = (const float*)d_in[0];     // [B,S,K] f32
  const float* w = (const float*)d_in[1];     // [N,K] f32
  const float* bias = (const float*)d_in[2];  // [N] f32
  float* out = (float*)d_out;                 // [M,N] f32 (bf16-rounded values)

  const int N = in_sizes[2];             // 4096 (D_OUT)
  const int K = in_sizes[1] / N;         // 4096 (D_IN)
  const int M = in_sizes[0] / K;         // 8192 tokens

  uint8_t* x8 = (uint8_t*)d_ws;                    // M*K bytes
  uint8_t* w8 = x8 + (size_t)M * K;                // N*K bytes
  float* asc = (float*)(w8 + (size_t)N * K);       // M floats
  float* wsc = asc + M;                            // N floats
  (void)ws_size; (void)n_in; (void)out_size;

  quant_all_kernel<<<M + N, 256, 0, stream>>>(x, w, x8, w8, asc, wsc, M, K);
  gemm_fp8_kernel<<<(M / BM) * (N / BN), 512, 0, stream>>>(x8, w8, asc, wsc, bias, out, M, N, K);
}